// Round 11
// baseline (516.034 us; speedup 1.0000x reference)
//
#include <hip/hip_runtime.h>
#include <hip/hip_bf16.h>

// Problem: S=2048, D_MODEL=2048, H=16, HD=128
// out = softmax1((q@Wq^T)(k@Wk^T)^T / sqrt(HD)) @ (v@Wv^T) * scalars @ Wo^T
//
// Round 17:
//  - POST-MORTEM r16: QBLK=128 dbuf attn worked (131->120us, total 512.6).
//  - Pipeline fusion: the V-projection GEMM (256 blocks = 1 block/CU on a
//    2/CU-capacity kernel, half-idle) is data-independent of the QK GEMM yet
//    ran serially after it. Fuse all three projections into ONE z=3 launch
//    (768 blocks, continuously 2/CU). Both convs merge into one 7-matrix
//    launch. 6 -> 4 dispatches. Needs 19 planes (152MB): runtime ws_size
//    check falls back to the 12-plane r16 flow if the workspace is smaller.
//  - gemm_nt3: OUTMODE template -> runtime per-GArgs field (block-uniform
//    branch) so one fused launch mixes hi/lo, bf16 and fp32 epilogues.
//    Inner loop byte-identical.
//  - attn_mfma: byte-identical to r16 (verified 120us, 88 VGPR).

#define S_LEN 2048
#define DMODEL 2048
#define NHEAD 16
#define HEADD 128

typedef __bf16 bf16x8 __attribute__((ext_vector_type(8)));
typedef __bf16 bf16x4 __attribute__((ext_vector_type(4)));
typedef float f32x4 __attribute__((ext_vector_type(4)));

__device__ inline void async_copy16(const __bf16* g, __bf16* l) {
    __builtin_amdgcn_global_load_lds(
        (const __attribute__((address_space(1))) unsigned int*)g,
        (__attribute__((address_space(3))) unsigned int*)l, 16, 0, 0);
}

// ---- fp32 -> hi/lo bf16 split conversion, up to 8 matrices per launch ----
struct CArgs {
    const float* s[8];
    __hip_bfloat16* h[8];
    __hip_bfloat16* l[8];
    float sc[8];
};

__global__ __launch_bounds__(256) void convN(CArgs a) {
    const int y = blockIdx.y;
    const float* s = a.s[y];
    __hip_bfloat16* ph = a.h[y];
    __hip_bfloat16* pl = a.l[y];
    const float sc = a.sc[y];
    size_t i4 = (size_t)blockIdx.x * 256 + threadIdx.x;  // float4 index
    float4 v = *(const float4*)&s[i4 * 4];
    float x0 = v.x * sc, x1 = v.y * sc, x2 = v.z * sc, x3 = v.w * sc;
    bf16x4 hv, lv;
    __bf16 a0 = (__bf16)x0, a1 = (__bf16)x1, a2 = (__bf16)x2, a3 = (__bf16)x3;
    hv[0] = a0; hv[1] = a1; hv[2] = a2; hv[3] = a3;
    lv[0] = (__bf16)(x0 - (float)a0); lv[1] = (__bf16)(x1 - (float)a1);
    lv[2] = (__bf16)(x2 - (float)a2); lv[3] = (__bf16)(x3 - (float)a3);
    *(bf16x4*)&ph[i4 * 4] = hv;
    *(bf16x4*)&pl[i4 * 4] = lv;
}

struct GArgs {
    const __bf16 *Ah, *Al, *Bh, *Bl;
    float* Cf;
    __bf16 *Ch, *Cl;
    int om;   // output mode: 0 = fp32, 1 = bf16, 2 = hi/lo planes
};

// ---- C = A @ B^T, pre-split hi/lo planes. Tile 128(M) x 128(N), BK=32.
// 256 threads = 4 waves in 2x2 grid; each wave owns a 64x64 sub-tile.
// Double-buffered LDS (64KB, 2 blocks/CU); one barrier per K-step.
// blockIdx.z picks g0/g1/g2; g.om picks the epilogue (block-uniform).
__global__ __launch_bounds__(256, 2) void gemm_nt3(GArgs g0, GArgs g1, GArgs g2) {
    constexpr int K = DMODEL, N = DMODEL;
    const GArgs g = blockIdx.z == 0 ? g0 : (blockIdx.z == 1 ? g1 : g2);
    __shared__ __bf16 sAh[2][128 * 32], sAl[2][128 * 32];
    __shared__ __bf16 sBh[2][128 * 32], sBl[2][128 * 32];

    const int tid = threadIdx.x;   // 0..255
    const int lane = tid & 63;
    const int wave = tid >> 6;     // 0..3
    const int wr = wave >> 1;      // wave-row (2)
    const int wc = wave & 1;       // wave-col (2)
    const int qr = lane & 15;
    const int quad = lane >> 4;

    // XCD-bijective swizzle over the 16x16 2D grid (nwg=256, %8==0):
    // consecutive swz ids share the same XCD and the same A-panel row block.
    const int flat = blockIdx.y * gridDim.x + blockIdx.x;
    const int swz = (flat & 7) * 32 + (flat >> 3);
    const size_t row0 = (size_t)(swz >> 4) * 128;
    const size_t col0 = (size_t)(swz & 15) * 128;

    // staging: chunk (c*256+tid) -> LDS row = c*64 + (tid>>2), slot = tid&3;
    // slot holds global k-chunk (slot ^ (row&3)); read undoes with quad^(qr&3).
    const int srow = tid >> 2;
    const int k8 = (((tid & 3) ^ ((tid >> 2) & 3)) * 8);
    const __bf16* gAh = g.Ah + (row0 + srow) * K + k8;
    const __bf16* gAl = g.Al + (row0 + srow) * K + k8;
    const __bf16* gBh = g.Bh + (col0 + srow) * K + k8;
    const __bf16* gBl = g.Bl + (col0 + srow) * K + k8;

    f32x4 acc[4][4] = {};

    // issue 8 global_load_lds (32KB) for K-tile at column k0 into buffer b
    auto stage = [&](int b, int k0) {
#pragma unroll
        for (int c = 0; c < 2; ++c) {
            async_copy16(gAh + k0 + (size_t)c * 64 * K, &sAh[b][c * 2048 + tid * 8]);
            async_copy16(gAl + k0 + (size_t)c * 64 * K, &sAl[b][c * 2048 + tid * 8]);
            async_copy16(gBh + k0 + (size_t)c * 64 * K, &sBh[b][c * 2048 + tid * 8]);
            async_copy16(gBl + k0 + (size_t)c * 64 * K, &sBl[b][c * 2048 + tid * 8]);
        }
    };

    stage(0, 0);
    __syncthreads();  // prologue drain: buf0 ready

    const int aslot = (quad ^ (qr & 3)) * 8;
    int cur = 0;
    for (int k0 = 0; k0 < K; k0 += 32) {
        if (k0 + 32 < K) stage(cur ^ 1, k0 + 32);  // prefetch next tile

        bf16x8 a_h[4], a_l[4], b_h[4], b_l[4];
#pragma unroll
        for (int i = 0; i < 4; ++i) {
            a_h[i] = *(const bf16x8*)&sAh[cur][(wr * 64 + i * 16 + qr) * 32 + aslot];
            a_l[i] = *(const bf16x8*)&sAl[cur][(wr * 64 + i * 16 + qr) * 32 + aslot];
        }
#pragma unroll
        for (int j = 0; j < 4; ++j) {
            b_h[j] = *(const bf16x8*)&sBh[cur][(wc * 64 + j * 16 + qr) * 32 + aslot];
            b_l[j] = *(const bf16x8*)&sBl[cur][(wc * 64 + j * 16 + qr) * 32 + aslot];
        }
#pragma unroll
        for (int i = 0; i < 4; ++i)
#pragma unroll
            for (int j = 0; j < 4; ++j) {
                acc[i][j] = __builtin_amdgcn_mfma_f32_16x16x32_bf16(a_h[i], b_h[j], acc[i][j], 0, 0, 0);
                acc[i][j] = __builtin_amdgcn_mfma_f32_16x16x32_bf16(a_h[i], b_l[j], acc[i][j], 0, 0, 0);
                acc[i][j] = __builtin_amdgcn_mfma_f32_16x16x32_bf16(a_l[i], b_h[j], acc[i][j], 0, 0, 0);
            }
        __syncthreads();  // prefetch landed (vmcnt) + all reads of buf[cur] done
        cur ^= 1;
    }

    // epilogue: C/D layout col=lane&15, row=quad*4+reg
#pragma unroll
    for (int i = 0; i < 4; ++i)
#pragma unroll
        for (int j = 0; j < 4; ++j)
#pragma unroll
            for (int r = 0; r < 4; ++r) {
                size_t idx = (row0 + wr * 64 + i * 16 + quad * 4 + r) * N +
                             col0 + wc * 64 + j * 16 + qr;
                float x = acc[i][j][r];
                if (g.om == 0) {
                    g.Cf[idx] = x;
                } else if (g.om == 1) {
                    g.Ch[idx] = (__bf16)x;
                } else {
                    __bf16 hv = (__bf16)x;
                    g.Ch[idx] = hv;
                    g.Cl[idx] = (__bf16)(x - (float)hv);
                }
            }
}

// MFMA flash attention. Block = 128 q-rows x 1 head; 8 waves x 16 rows each.
// = r16 verified version (120us, 88 VGPR): QBLK=128, double-buffered K/V LDS
// (123KB, 1 block/CU), 1 barrier/tile, T14 reg prefetch, head-local swizzle.
__global__ __launch_bounds__(512) void attn_mfma(const __bf16* __restrict__ qhi_g,
                                                 const __bf16* __restrict__ qlo_g,
                                                 const __bf16* __restrict__ khi_g,
                                                 const __bf16* __restrict__ klo_g,
                                                 const __bf16* __restrict__ vhT,
                                                 const float* __restrict__ scalars,
                                                 __bf16* __restrict__ ohi_g,
                                                 __bf16* __restrict__ olo_g) {
    // head-locality XCD swizzle: XCD x (= flatb%8 dispatch round-robin) owns
    // heads {2x, 2x+1}; K/V working set per XCD = 2.5MB < 4MB L2. Bijective.
    const int flatb = blockIdx.y * gridDim.x + blockIdx.x;  // 0..255
    const int ib = flatb >> 3;                              // 0..31
    const int h = (flatb & 7) * 2 + (ib >> 4);
    const int q0 = (ib & 15) * 128;

    __shared__ __align__(16) __bf16 Khi[2][64][136];  // padded: 272B stride
    __shared__ __align__(16) __bf16 Klo[2][64][136];
    __shared__ __align__(16) __bf16 VT[2][128][72];   // [head-dim][kpos]
    __shared__ __align__(16) __bf16 Ps[128][72];      // [q-row][kpos] wave-private rows

    const int tid = threadIdx.x;   // 0..511
    const int lane = tid & 63;
    const int wave = tid >> 6;     // 0..7
    const int qr = lane & 15;
    const int quad = lane >> 4;

    // per-thread staging coordinates (fixed across tiles), 512-thread layout
    const int kp0 = tid >> 4;           // 0..31; K rows kp0, kp0+32
    const int kc8 = (tid & 15) * 8;     // K col byte-slot (128 cols)
    const int dm0 = tid >> 3;           // 0..63; V rows dm0, dm0+64
    const int vc8 = (tid & 7) * 8;      // V col slot (64 cols)
    const __bf16* gK_hi = khi_g + (size_t)kp0 * DMODEL + h * HEADD + kc8;
    const __bf16* gK_lo = klo_g + (size_t)kp0 * DMODEL + h * HEADD + kc8;
    const __bf16* gVT = vhT + (size_t)(h * HEADD + dm0) * S_LEN + vc8;

    bf16x8 qfh[4], qfl[4];
    {
        const __bf16* qrh = qhi_g + (size_t)(q0 + wave * 16 + qr) * DMODEL + h * HEADD;
        const __bf16* qrl = qlo_g + (size_t)(q0 + wave * 16 + qr) * DMODEL + h * HEADD;
#pragma unroll
        for (int kc = 0; kc < 4; ++kc) {
            qfh[kc] = *(const bf16x8*)&qrh[kc * 32 + quad * 8];
            qfl[kc] = *(const bf16x8*)&qrl[kc * 32 + quad * 8];
        }
    }

    // register-staged K/V tile (T14 async split): 6 x 16B per thread
    bf16x8 rKh[2], rKl[2], rV[2];
    auto load_regs = [&](int k0) {
#pragma unroll
        for (int i = 0; i < 2; ++i) {
            size_t go = (size_t)(k0 + i * 32) * DMODEL;
            rKh[i] = *(const bf16x8*)&gK_hi[go];
            rKl[i] = *(const bf16x8*)&gK_lo[go];
            rV[i] = *(const bf16x8*)&gVT[(size_t)(i * 64) * S_LEN + k0];
        }
    };
    auto write_lds = [&](int b) {
#pragma unroll
        for (int i = 0; i < 2; ++i) {
            *(bf16x8*)&Khi[b][kp0 + i * 32][kc8] = rKh[i];
            *(bf16x8*)&Klo[b][kp0 + i * 32][kc8] = rKl[i];
            *(bf16x8*)&VT[b][dm0 + i * 64][vc8] = rV[i];
        }
    };

    f32x4 oacc[8] = {};
    float m_r[4], l_r[4];
#pragma unroll
    for (int r = 0; r < 4; ++r) { m_r[r] = 0.f; l_r[r] = 1.f; }  // softmax1 init

    load_regs(0);
    write_lds(0);
    int cur = 0;
    for (int k0 = 0; k0 < S_LEN; k0 += 64) {
        __syncthreads();  // buf[cur] writes visible; prior reads of cur^1 done
        if (k0 + 64 < S_LEN) load_regs(k0 + 64);  // next tile -> regs (async)

        f32x4 S[4] = {};
#pragma unroll
        for (int jt = 0; jt < 4; ++jt) {
#pragma unroll
            for (int kc = 0; kc < 4; ++kc) {
                bf16x8 kh8 = *(const bf16x8*)&Khi[cur][jt * 16 + qr][kc * 32 + quad * 8];
                bf16x8 kl8 = *(const bf16x8*)&Klo[cur][jt * 16 + qr][kc * 32 + quad * 8];
                S[jt] = __builtin_amdgcn_mfma_f32_16x16x32_bf16(qfh[kc], kh8, S[jt], 0, 0, 0);
                S[jt] = __builtin_amdgcn_mfma_f32_16x16x32_bf16(qfh[kc], kl8, S[jt], 0, 0, 0);
                S[jt] = __builtin_amdgcn_mfma_f32_16x16x32_bf16(qfl[kc], kh8, S[jt], 0, 0, 0);
            }
        }

#pragma unroll
        for (int r = 0; r < 4; ++r) {
            float mx = fmaxf(fmaxf(S[0][r], S[1][r]), fmaxf(S[2][r], S[3][r]));
#pragma unroll
            for (int m = 1; m < 16; m <<= 1) mx = fmaxf(mx, __shfl_xor(mx, m, 64));
            float m_new = fmaxf(m_r[r], mx);
            float alpha = __expf(m_r[r] - m_new);
            float sum = 0.f;
            int prow = wave * 16 + quad * 4 + r;
#pragma unroll
            for (int jt = 0; jt < 4; ++jt) {
                float e = __expf(S[jt][r] - m_new);
                sum += e;
                Ps[prow][jt * 16 + qr] = (__bf16)e;
            }
#pragma unroll
            for (int m = 1; m < 16; m <<= 1) sum += __shfl_xor(sum, m, 64);
            l_r[r] = l_r[r] * alpha + sum;
            m_r[r] = m_new;
#pragma unroll
            for (int nt = 0; nt < 8; ++nt) oacc[nt][r] *= alpha;
        }
        // NO barrier: Ps rows [wave*16, wave*16+16) are wave-private.

#pragma unroll
        for (int kc = 0; kc < 2; ++kc) {
            bf16x8 pf = *(const bf16x8*)&Ps[wave * 16 + qr][kc * 32 + quad * 8];
#pragma unroll
            for (int nt = 0; nt < 8; ++nt) {
                bf16x8 vf = *(const bf16x8*)&VT[cur][nt * 16 + qr][kc * 32 + quad * 8];
                oacc[nt] = __builtin_amdgcn_mfma_f32_16x16x32_bf16(pf, vf, oacc[nt], 0, 0, 0);
            }
        }

        if (k0 + 64 < S_LEN) write_lds(cur ^ 1);  // other buffer: no race with
        cur ^= 1;                                 // this tile's readers
    }

    const float sh = scalars[h];
#pragma unroll
    for (int r = 0; r < 4; ++r) {
        float wm = sh / l_r[r];
        size_t rowoff = (size_t)(q0 + wave * 16 + quad * 4 + r) * DMODEL + h * HEADD;
#pragma unroll
        for (int nt = 0; nt < 8; ++nt) {
            float x = oacc[nt][r] * wm;
            __bf16 hv = (__bf16)x;
            ohi_g[rowoff + nt * 16 + qr] = hv;
            olo_g[rowoff + nt * 16 + qr] = (__bf16)(x - (float)hv);
        }
    }
}

extern "C" void kernel_launch(void* const* d_in, const int* in_sizes, int n_in,
                              void* d_out, int out_size, void* d_ws, size_t ws_size,
                              hipStream_t stream) {
    const float* query   = (const float*)d_in[0];
    const float* key_    = (const float*)d_in[1];
    const float* value   = (const float*)d_in[2];
    const float* Wq      = (const float*)d_in[3];
    const float* Wk      = (const float*)d_in[4];
    const float* Wv      = (const float*)d_in[5];
    const float* Wo      = (const float*)d_in[6];
    const float* scalars = (const float*)d_in[7];
    float* out = (float*)d_out;

    const size_t PL = (size_t)S_LEN * DMODEL;  // elements per 8 MB plane
    __bf16* p[19];
    for (int i = 0; i < 19; ++i) p[i] = (__bf16*)d_ws + i * PL;

    const float scale = 0.08838834764831844f;  // 1/sqrt(128)
    dim3 gg(DMODEL / 128, S_LEN / 128, 1), gb(256);
    dim3 gg2(DMODEL / 128, S_LEN / 128, 2);
    dim3 gg3(DMODEL / 128, S_LEN / 128, 3);
    const int cgx = 2048 * 2048 / 4 / 256;

#define BH(x) (__hip_bfloat16*)(x)
    if (ws_size >= 19 * PL * sizeof(__bf16)) {
        // ---- fused path: 4 dispatches ----
        // planes: 0,1=q 2,3=Wq 4,5=k 6,7=Wk 8..11=QK out 12,13=Wv
        //         14,15=value 16,17=Wo 18=vhT
        {   // all 7 input conversions in one launch
            CArgs ca;
            ca.s[0] = query;  ca.h[0] = BH(p[0]);  ca.l[0] = BH(p[1]);  ca.sc[0] = 1.0f;
            ca.s[1] = Wq;     ca.h[1] = BH(p[2]);  ca.l[1] = BH(p[3]);  ca.sc[1] = scale;
            ca.s[2] = key_;   ca.h[2] = BH(p[4]);  ca.l[2] = BH(p[5]);  ca.sc[2] = 1.0f;
            ca.s[3] = Wk;     ca.h[3] = BH(p[6]);  ca.l[3] = BH(p[7]);  ca.sc[3] = 1.0f;
            ca.s[4] = Wv;     ca.h[4] = BH(p[12]); ca.l[4] = BH(p[13]); ca.sc[4] = 1.0f;
            ca.s[5] = value;  ca.h[5] = BH(p[14]); ca.l[5] = BH(p[15]); ca.sc[5] = 1.0f;
            ca.s[6] = Wo;     ca.h[6] = BH(p[16]); ca.l[6] = BH(p[17]); ca.sc[6] = 1.0f;
            ca.s[7] = Wo;     ca.h[7] = BH(p[16]); ca.l[7] = BH(p[17]); ca.sc[7] = 1.0f;
            convN<<<dim3(cgx, 7), 256, 0, stream>>>(ca);
        }
        {   // all three projections in one z=3 launch (Q, K, V independent)
            GArgs gq = {p[0], p[1], p[2], p[3], nullptr, p[8], p[9], 2};
            GArgs gk = {p[4], p[5], p[6], p[7], nullptr, p[10], p[11], 2};
            // vhT = (value @ Wv^T)^T = Wv @ value^T  (A = Wv, B = value)
            GArgs gv = {p[12], p[13], p[14], p[15], nullptr, p[18], nullptr, 1};
            gemm_nt3<<<gg3, gb, 0, stream>>>(gq, gk, gv);
        }
        attn_mfma<<<dim3(S_LEN / 128, NHEAD), 512, 0, stream>>>(
            p[8], p[9], p[10], p[11], p[18], scalars, p[8], p[9]);
        {   // out = attn_out @ Wo^T
            GArgs go = {p[8], p[9], p[16], p[17], out, nullptr, nullptr, 0};
            gemm_nt3<<<gg, gb, 0, stream>>>(go, go, go);
        }
    } else {
        // ---- fallback: r16 12-plane flow (verified 512.6us) ----
        {   // q, Wq (scale folded), key, Wk
            CArgs ca;
            ca.s[0] = query; ca.h[0] = BH(p[0]); ca.l[0] = BH(p[1]); ca.sc[0] = 1.0f;
            ca.s[1] = Wq;    ca.h[1] = BH(p[2]); ca.l[1] = BH(p[3]); ca.sc[1] = scale;
            ca.s[2] = key_;  ca.h[2] = BH(p[4]); ca.l[2] = BH(p[5]); ca.sc[2] = 1.0f;
            ca.s[3] = Wk;    ca.h[3] = BH(p[6]); ca.l[3] = BH(p[7]); ca.sc[3] = 1.0f;
            convN<<<dim3(cgx, 4), 256, 0, stream>>>(ca);
        }
        {   // fused Q/K projections
            GArgs gq = {p[0], p[1], p[2], p[3], nullptr, p[8], p[9], 2};
            GArgs gk = {p[4], p[5], p[6], p[7], nullptr, p[10], p[11], 2};
            gemm_nt3<<<gg2, gb, 0, stream>>>(gq, gk, gk);
        }
        {   // Wv, value, Wo (into p6/p7, freed by QK gemm)
            CArgs cc;
            cc.s[0] = Wv;    cc.h[0] = BH(p[0]); cc.l[0] = BH(p[1]); cc.sc[0] = 1.0f;
            cc.s[1] = value; cc.h[1] = BH(p[2]); cc.l[1] = BH(p[3]); cc.sc[1] = 1.0f;
            cc.s[2] = Wo;    cc.h[2] = BH(p[6]); cc.l[2] = BH(p[7]); cc.sc[2] = 1.0f;
            convN<<<dim3(cgx, 3), 256, 0, stream>>>(cc);
        }
        {   // vhT = Wv @ value^T
            GArgs gv = {p[0], p[1], p[2], p[3], nullptr, p[4], nullptr, 1};
            gemm_nt3<<<gg, gb, 0, stream>>>(gv, gv, gv);
        }
        attn_mfma<<<dim3(S_LEN / 128, NHEAD), 512, 0, stream>>>(
            p[8], p[9], p[10], p[11], p[4], scalars, p[8], p[9]);
        {   // out = attn_out @ Wo^T
            GArgs go = {p[8], p[9], p[6], p[7], out, nullptr, nullptr, 0};
            gemm_nt3<<<gg, gb, 0, stream>>>(go, go, go);
        }
    }
#undef BH
}

// Round 12
// 505.689 us; speedup vs baseline: 1.0205x; 1.0205x over previous
//
#include <hip/hip_runtime.h>
#include <hip/hip_bf16.h>

// Problem: S=2048, D_MODEL=2048, H=16, HD=128
// out = softmax1((q@Wq^T)(k@Wk^T)^T / sqrt(HD)) @ (v@Wv^T) * scalars @ Wo^T
//
// Round 18:
//  - POST-MORTEM r17: proj fusion a wash (fused proj 199us = 782 TF eff,
//    at the m97-structure ceiling). Accounting shows the O GEMM is ~150us:
//    256 blocks = 1 block/CU on a kernel that needs 2 co-resident blocks
//    for latency hiding.
//  - Split-K=2 for O: GArgs gains runtime kn; O launches z=2 (512 blocks,
//    2/CU), halves of K write partial fp32 to free planes; float4 add kernel
//    reduces. Inner GEMM loop byte-identical (only loop bound is runtime).
//  - attn_mfma / convN: byte-identical to r17.

#define S_LEN 2048
#define DMODEL 2048
#define NHEAD 16
#define HEADD 128

typedef __bf16 bf16x8 __attribute__((ext_vector_type(8)));
typedef __bf16 bf16x4 __attribute__((ext_vector_type(4)));
typedef float f32x4 __attribute__((ext_vector_type(4)));

__device__ inline void async_copy16(const __bf16* g, __bf16* l) {
    __builtin_amdgcn_global_load_lds(
        (const __attribute__((address_space(1))) unsigned int*)g,
        (__attribute__((address_space(3))) unsigned int*)l, 16, 0, 0);
}

// ---- fp32 -> hi/lo bf16 split conversion, up to 8 matrices per launch ----
struct CArgs {
    const float* s[8];
    __hip_bfloat16* h[8];
    __hip_bfloat16* l[8];
    float sc[8];
};

__global__ __launch_bounds__(256) void convN(CArgs a) {
    const int y = blockIdx.y;
    const float* s = a.s[y];
    __hip_bfloat16* ph = a.h[y];
    __hip_bfloat16* pl = a.l[y];
    const float sc = a.sc[y];
    size_t i4 = (size_t)blockIdx.x * 256 + threadIdx.x;  // float4 index
    float4 v = *(const float4*)&s[i4 * 4];
    float x0 = v.x * sc, x1 = v.y * sc, x2 = v.z * sc, x3 = v.w * sc;
    bf16x4 hv, lv;
    __bf16 a0 = (__bf16)x0, a1 = (__bf16)x1, a2 = (__bf16)x2, a3 = (__bf16)x3;
    hv[0] = a0; hv[1] = a1; hv[2] = a2; hv[3] = a3;
    lv[0] = (__bf16)(x0 - (float)a0); lv[1] = (__bf16)(x1 - (float)a1);
    lv[2] = (__bf16)(x2 - (float)a2); lv[3] = (__bf16)(x3 - (float)a3);
    *(bf16x4*)&ph[i4 * 4] = hv;
    *(bf16x4*)&pl[i4 * 4] = lv;
}

// ---- out = a + b (fp32, float4 per thread) — split-K reduction ----
__global__ __launch_bounds__(256) void addf4(float* __restrict__ o,
                                             const float* __restrict__ a,
                                             const float* __restrict__ b) {
    size_t i4 = (size_t)blockIdx.x * 256 + threadIdx.x;
    float4 va = *(const float4*)&a[i4 * 4];
    float4 vb = *(const float4*)&b[i4 * 4];
    float4 vo = {va.x + vb.x, va.y + vb.y, va.z + vb.z, va.w + vb.w};
    *(float4*)&o[i4 * 4] = vo;
}

struct GArgs {
    const __bf16 *Ah, *Al, *Bh, *Bl;
    float* Cf;
    __bf16 *Ch, *Cl;
    int om;   // output mode: 0 = fp32, 1 = bf16, 2 = hi/lo planes
    int kn;   // K extent for this slice (row stride stays DMODEL)
};

// ---- C = A @ B^T, pre-split hi/lo planes. Tile 128(M) x 128(N), BK=32.
// 256 threads = 4 waves in 2x2 grid; each wave owns a 64x64 sub-tile.
// Double-buffered LDS (64KB, 2 blocks/CU); one barrier per K-step.
// blockIdx.z picks g0/g1/g2; g.om picks the epilogue (block-uniform);
// g.kn is the K extent (split-K slices pass pre-offset base pointers).
__global__ __launch_bounds__(256, 2) void gemm_nt3(GArgs g0, GArgs g1, GArgs g2) {
    constexpr int K = DMODEL, N = DMODEL;
    const GArgs g = blockIdx.z == 0 ? g0 : (blockIdx.z == 1 ? g1 : g2);
    __shared__ __bf16 sAh[2][128 * 32], sAl[2][128 * 32];
    __shared__ __bf16 sBh[2][128 * 32], sBl[2][128 * 32];

    const int tid = threadIdx.x;   // 0..255
    const int lane = tid & 63;
    const int wave = tid >> 6;     // 0..3
    const int wr = wave >> 1;      // wave-row (2)
    const int wc = wave & 1;       // wave-col (2)
    const int qr = lane & 15;
    const int quad = lane >> 4;

    // XCD-bijective swizzle over the 16x16 2D grid (nwg=256, %8==0):
    // consecutive swz ids share the same XCD and the same A-panel row block.
    const int flat = blockIdx.y * gridDim.x + blockIdx.x;
    const int swz = (flat & 7) * 32 + (flat >> 3);
    const size_t row0 = (size_t)(swz >> 4) * 128;
    const size_t col0 = (size_t)(swz & 15) * 128;

    // staging: chunk (c*256+tid) -> LDS row = c*64 + (tid>>2), slot = tid&3;
    // slot holds global k-chunk (slot ^ (row&3)); read undoes with quad^(qr&3).
    const int srow = tid >> 2;
    const int k8 = (((tid & 3) ^ ((tid >> 2) & 3)) * 8);
    const __bf16* gAh = g.Ah + (row0 + srow) * K + k8;
    const __bf16* gAl = g.Al + (row0 + srow) * K + k8;
    const __bf16* gBh = g.Bh + (col0 + srow) * K + k8;
    const __bf16* gBl = g.Bl + (col0 + srow) * K + k8;

    f32x4 acc[4][4] = {};

    // issue 8 global_load_lds (32KB) for K-tile at column k0 into buffer b
    auto stage = [&](int b, int k0) {
#pragma unroll
        for (int c = 0; c < 2; ++c) {
            async_copy16(gAh + k0 + (size_t)c * 64 * K, &sAh[b][c * 2048 + tid * 8]);
            async_copy16(gAl + k0 + (size_t)c * 64 * K, &sAl[b][c * 2048 + tid * 8]);
            async_copy16(gBh + k0 + (size_t)c * 64 * K, &sBh[b][c * 2048 + tid * 8]);
            async_copy16(gBl + k0 + (size_t)c * 64 * K, &sBl[b][c * 2048 + tid * 8]);
        }
    };

    stage(0, 0);
    __syncthreads();  // prologue drain: buf0 ready

    const int aslot = (quad ^ (qr & 3)) * 8;
    int cur = 0;
    for (int k0 = 0; k0 < g.kn; k0 += 32) {
        if (k0 + 32 < g.kn) stage(cur ^ 1, k0 + 32);  // prefetch next tile

        bf16x8 a_h[4], a_l[4], b_h[4], b_l[4];
#pragma unroll
        for (int i = 0; i < 4; ++i) {
            a_h[i] = *(const bf16x8*)&sAh[cur][(wr * 64 + i * 16 + qr) * 32 + aslot];
            a_l[i] = *(const bf16x8*)&sAl[cur][(wr * 64 + i * 16 + qr) * 32 + aslot];
        }
#pragma unroll
        for (int j = 0; j < 4; ++j) {
            b_h[j] = *(const bf16x8*)&sBh[cur][(wc * 64 + j * 16 + qr) * 32 + aslot];
            b_l[j] = *(const bf16x8*)&sBl[cur][(wc * 64 + j * 16 + qr) * 32 + aslot];
        }
#pragma unroll
        for (int i = 0; i < 4; ++i)
#pragma unroll
            for (int j = 0; j < 4; ++j) {
                acc[i][j] = __builtin_amdgcn_mfma_f32_16x16x32_bf16(a_h[i], b_h[j], acc[i][j], 0, 0, 0);
                acc[i][j] = __builtin_amdgcn_mfma_f32_16x16x32_bf16(a_h[i], b_l[j], acc[i][j], 0, 0, 0);
                acc[i][j] = __builtin_amdgcn_mfma_f32_16x16x32_bf16(a_l[i], b_h[j], acc[i][j], 0, 0, 0);
            }
        __syncthreads();  // prefetch landed (vmcnt) + all reads of buf[cur] done
        cur ^= 1;
    }

    // epilogue: C/D layout col=lane&15, row=quad*4+reg
#pragma unroll
    for (int i = 0; i < 4; ++i)
#pragma unroll
        for (int j = 0; j < 4; ++j)
#pragma unroll
            for (int r = 0; r < 4; ++r) {
                size_t idx = (row0 + wr * 64 + i * 16 + quad * 4 + r) * N +
                             col0 + wc * 64 + j * 16 + qr;
                float x = acc[i][j][r];
                if (g.om == 0) {
                    g.Cf[idx] = x;
                } else if (g.om == 1) {
                    g.Ch[idx] = (__bf16)x;
                } else {
                    __bf16 hv = (__bf16)x;
                    g.Ch[idx] = hv;
                    g.Cl[idx] = (__bf16)(x - (float)hv);
                }
            }
}

// MFMA flash attention. Block = 128 q-rows x 1 head; 8 waves x 16 rows each.
// = r16 verified version (120us, 88 VGPR): QBLK=128, double-buffered K/V LDS
// (123KB, 1 block/CU), 1 barrier/tile, T14 reg prefetch, head-local swizzle.
__global__ __launch_bounds__(512) void attn_mfma(const __bf16* __restrict__ qhi_g,
                                                 const __bf16* __restrict__ qlo_g,
                                                 const __bf16* __restrict__ khi_g,
                                                 const __bf16* __restrict__ klo_g,
                                                 const __bf16* __restrict__ vhT,
                                                 const float* __restrict__ scalars,
                                                 __bf16* __restrict__ ohi_g,
                                                 __bf16* __restrict__ olo_g) {
    // head-locality XCD swizzle: XCD x (= flatb%8 dispatch round-robin) owns
    // heads {2x, 2x+1}; K/V working set per XCD = 2.5MB < 4MB L2. Bijective.
    const int flatb = blockIdx.y * gridDim.x + blockIdx.x;  // 0..255
    const int ib = flatb >> 3;                              // 0..31
    const int h = (flatb & 7) * 2 + (ib >> 4);
    const int q0 = (ib & 15) * 128;

    __shared__ __align__(16) __bf16 Khi[2][64][136];  // padded: 272B stride
    __shared__ __align__(16) __bf16 Klo[2][64][136];
    __shared__ __align__(16) __bf16 VT[2][128][72];   // [head-dim][kpos]
    __shared__ __align__(16) __bf16 Ps[128][72];      // [q-row][kpos] wave-private rows

    const int tid = threadIdx.x;   // 0..511
    const int lane = tid & 63;
    const int wave = tid >> 6;     // 0..7
    const int qr = lane & 15;
    const int quad = lane >> 4;

    // per-thread staging coordinates (fixed across tiles), 512-thread layout
    const int kp0 = tid >> 4;           // 0..31; K rows kp0, kp0+32
    const int kc8 = (tid & 15) * 8;     // K col byte-slot (128 cols)
    const int dm0 = tid >> 3;           // 0..63; V rows dm0, dm0+64
    const int vc8 = (tid & 7) * 8;      // V col slot (64 cols)
    const __bf16* gK_hi = khi_g + (size_t)kp0 * DMODEL + h * HEADD + kc8;
    const __bf16* gK_lo = klo_g + (size_t)kp0 * DMODEL + h * HEADD + kc8;
    const __bf16* gVT = vhT + (size_t)(h * HEADD + dm0) * S_LEN + vc8;

    bf16x8 qfh[4], qfl[4];
    {
        const __bf16* qrh = qhi_g + (size_t)(q0 + wave * 16 + qr) * DMODEL + h * HEADD;
        const __bf16* qrl = qlo_g + (size_t)(q0 + wave * 16 + qr) * DMODEL + h * HEADD;
#pragma unroll
        for (int kc = 0; kc < 4; ++kc) {
            qfh[kc] = *(const bf16x8*)&qrh[kc * 32 + quad * 8];
            qfl[kc] = *(const bf16x8*)&qrl[kc * 32 + quad * 8];
        }
    }

    // register-staged K/V tile (T14 async split): 6 x 16B per thread
    bf16x8 rKh[2], rKl[2], rV[2];
    auto load_regs = [&](int k0) {
#pragma unroll
        for (int i = 0; i < 2; ++i) {
            size_t go = (size_t)(k0 + i * 32) * DMODEL;
            rKh[i] = *(const bf16x8*)&gK_hi[go];
            rKl[i] = *(const bf16x8*)&gK_lo[go];
            rV[i] = *(const bf16x8*)&gVT[(size_t)(i * 64) * S_LEN + k0];
        }
    };
    auto write_lds = [&](int b) {
#pragma unroll
        for (int i = 0; i < 2; ++i) {
            *(bf16x8*)&Khi[b][kp0 + i * 32][kc8] = rKh[i];
            *(bf16x8*)&Klo[b][kp0 + i * 32][kc8] = rKl[i];
            *(bf16x8*)&VT[b][dm0 + i * 64][vc8] = rV[i];
        }
    };

    f32x4 oacc[8] = {};
    float m_r[4], l_r[4];
#pragma unroll
    for (int r = 0; r < 4; ++r) { m_r[r] = 0.f; l_r[r] = 1.f; }  // softmax1 init

    load_regs(0);
    write_lds(0);
    int cur = 0;
    for (int k0 = 0; k0 < S_LEN; k0 += 64) {
        __syncthreads();  // buf[cur] writes visible; prior reads of cur^1 done
        if (k0 + 64 < S_LEN) load_regs(k0 + 64);  // next tile -> regs (async)

        f32x4 S[4] = {};
#pragma unroll
        for (int jt = 0; jt < 4; ++jt) {
#pragma unroll
            for (int kc = 0; kc < 4; ++kc) {
                bf16x8 kh8 = *(const bf16x8*)&Khi[cur][jt * 16 + qr][kc * 32 + quad * 8];
                bf16x8 kl8 = *(const bf16x8*)&Klo[cur][jt * 16 + qr][kc * 32 + quad * 8];
                S[jt] = __builtin_amdgcn_mfma_f32_16x16x32_bf16(qfh[kc], kh8, S[jt], 0, 0, 0);
                S[jt] = __builtin_amdgcn_mfma_f32_16x16x32_bf16(qfh[kc], kl8, S[jt], 0, 0, 0);
                S[jt] = __builtin_amdgcn_mfma_f32_16x16x32_bf16(qfl[kc], kh8, S[jt], 0, 0, 0);
            }
        }

#pragma unroll
        for (int r = 0; r < 4; ++r) {
            float mx = fmaxf(fmaxf(S[0][r], S[1][r]), fmaxf(S[2][r], S[3][r]));
#pragma unroll
            for (int m = 1; m < 16; m <<= 1) mx = fmaxf(mx, __shfl_xor(mx, m, 64));
            float m_new = fmaxf(m_r[r], mx);
            float alpha = __expf(m_r[r] - m_new);
            float sum = 0.f;
            int prow = wave * 16 + quad * 4 + r;
#pragma unroll
            for (int jt = 0; jt < 4; ++jt) {
                float e = __expf(S[jt][r] - m_new);
                sum += e;
                Ps[prow][jt * 16 + qr] = (__bf16)e;
            }
#pragma unroll
            for (int m = 1; m < 16; m <<= 1) sum += __shfl_xor(sum, m, 64);
            l_r[r] = l_r[r] * alpha + sum;
            m_r[r] = m_new;
#pragma unroll
            for (int nt = 0; nt < 8; ++nt) oacc[nt][r] *= alpha;
        }
        // NO barrier: Ps rows [wave*16, wave*16+16) are wave-private.

#pragma unroll
        for (int kc = 0; kc < 2; ++kc) {
            bf16x8 pf = *(const bf16x8*)&Ps[wave * 16 + qr][kc * 32 + quad * 8];
#pragma unroll
            for (int nt = 0; nt < 8; ++nt) {
                bf16x8 vf = *(const bf16x8*)&VT[cur][nt * 16 + qr][kc * 32 + quad * 8];
                oacc[nt] = __builtin_amdgcn_mfma_f32_16x16x32_bf16(pf, vf, oacc[nt], 0, 0, 0);
            }
        }

        if (k0 + 64 < S_LEN) write_lds(cur ^ 1);  // other buffer: no race with
        cur ^= 1;                                 // this tile's readers
    }

    const float sh = scalars[h];
#pragma unroll
    for (int r = 0; r < 4; ++r) {
        float wm = sh / l_r[r];
        size_t rowoff = (size_t)(q0 + wave * 16 + quad * 4 + r) * DMODEL + h * HEADD;
#pragma unroll
        for (int nt = 0; nt < 8; ++nt) {
            float x = oacc[nt][r] * wm;
            __bf16 hv = (__bf16)x;
            ohi_g[rowoff + nt * 16 + qr] = hv;
            olo_g[rowoff + nt * 16 + qr] = (__bf16)(x - (float)hv);
        }
    }
}

extern "C" void kernel_launch(void* const* d_in, const int* in_sizes, int n_in,
                              void* d_out, int out_size, void* d_ws, size_t ws_size,
                              hipStream_t stream) {
    const float* query   = (const float*)d_in[0];
    const float* key_    = (const float*)d_in[1];
    const float* value   = (const float*)d_in[2];
    const float* Wq      = (const float*)d_in[3];
    const float* Wk      = (const float*)d_in[4];
    const float* Wv      = (const float*)d_in[5];
    const float* Wo      = (const float*)d_in[6];
    const float* scalars = (const float*)d_in[7];
    float* out = (float*)d_out;

    const size_t PL = (size_t)S_LEN * DMODEL;  // elements per 8 MB plane
    __bf16* p[19];
    for (int i = 0; i < 19; ++i) p[i] = (__bf16*)d_ws + i * PL;

    const float scale = 0.08838834764831844f;  // 1/sqrt(128)
    dim3 gg(DMODEL / 128, S_LEN / 128, 1), gb(256);
    dim3 gg2(DMODEL / 128, S_LEN / 128, 2);
    dim3 gg3(DMODEL / 128, S_LEN / 128, 3);
    const int cgx = 2048 * 2048 / 4 / 256;

#define BH(x) (__hip_bfloat16*)(x)
    if (ws_size >= 19 * PL * sizeof(__bf16)) {
        // ---- fused path: 5 dispatches ----
        // planes: 0,1=q 2,3=Wq 4,5=k 6,7=Wk 8..11=QK out 12,13=Wv
        //         14,15=value 16,17=Wo 18=vhT
        // after proj gemm, planes 0-3 are free -> split-K fp32 partials
        //   part0 = planes 0-1, part1 = planes 2-3 (each exactly 16.8MB)
        {   // all 7 input conversions in one launch
            CArgs ca;
            ca.s[0] = query;  ca.h[0] = BH(p[0]);  ca.l[0] = BH(p[1]);  ca.sc[0] = 1.0f;
            ca.s[1] = Wq;     ca.h[1] = BH(p[2]);  ca.l[1] = BH(p[3]);  ca.sc[1] = scale;
            ca.s[2] = key_;   ca.h[2] = BH(p[4]);  ca.l[2] = BH(p[5]);  ca.sc[2] = 1.0f;
            ca.s[3] = Wk;     ca.h[3] = BH(p[6]);  ca.l[3] = BH(p[7]);  ca.sc[3] = 1.0f;
            ca.s[4] = Wv;     ca.h[4] = BH(p[12]); ca.l[4] = BH(p[13]); ca.sc[4] = 1.0f;
            ca.s[5] = value;  ca.h[5] = BH(p[14]); ca.l[5] = BH(p[15]); ca.sc[5] = 1.0f;
            ca.s[6] = Wo;     ca.h[6] = BH(p[16]); ca.l[6] = BH(p[17]); ca.sc[6] = 1.0f;
            ca.s[7] = Wo;     ca.h[7] = BH(p[16]); ca.l[7] = BH(p[17]); ca.sc[7] = 1.0f;
            convN<<<dim3(cgx, 7), 256, 0, stream>>>(ca);
        }
        {   // all three projections in one z=3 launch (Q, K, V independent)
            GArgs gq = {p[0], p[1], p[2], p[3], nullptr, p[8], p[9], 2, DMODEL};
            GArgs gk = {p[4], p[5], p[6], p[7], nullptr, p[10], p[11], 2, DMODEL};
            // vhT = (value @ Wv^T)^T = Wv @ value^T  (A = Wv, B = value)
            GArgs gv = {p[12], p[13], p[14], p[15], nullptr, p[18], nullptr, 1, DMODEL};
            gemm_nt3<<<gg3, gb, 0, stream>>>(gq, gk, gv);
        }
        attn_mfma<<<dim3(S_LEN / 128, NHEAD), 512, 0, stream>>>(
            p[8], p[9], p[10], p[11], p[18], scalars, p[8], p[9]);
        {   // out = attn_out @ Wo^T, split-K=2 (512 blocks = 2/CU)
            float* part0 = (float*)p[0];
            float* part1 = (float*)p[2];
            GArgs go0 = {p[8], p[9], p[16], p[17], part0, nullptr, nullptr, 0, 1024};
            GArgs go1 = {p[8] + 1024, p[9] + 1024, p[16] + 1024, p[17] + 1024,
                         part1, nullptr, nullptr, 0, 1024};
            gemm_nt3<<<gg2, gb, 0, stream>>>(go0, go1, go1);
            addf4<<<dim3(2048 * 2048 / 4 / 256), 256, 0, stream>>>(out, part0, part1);
        }
    } else {
        // ---- fallback: 12-plane flow ----
        {   // q, Wq (scale folded), key, Wk
            CArgs ca;
            ca.s[0] = query; ca.h[0] = BH(p[0]); ca.l[0] = BH(p[1]); ca.sc[0] = 1.0f;
            ca.s[1] = Wq;    ca.h[1] = BH(p[2]); ca.l[1] = BH(p[3]); ca.sc[1] = scale;
            ca.s[2] = key_;  ca.h[2] = BH(p[4]); ca.l[2] = BH(p[5]); ca.sc[2] = 1.0f;
            ca.s[3] = Wk;    ca.h[3] = BH(p[6]); ca.l[3] = BH(p[7]); ca.sc[3] = 1.0f;
            convN<<<dim3(cgx, 4), 256, 0, stream>>>(ca);
        }
        {   // fused Q/K projections
            GArgs gq = {p[0], p[1], p[2], p[3], nullptr, p[8], p[9], 2, DMODEL};
            GArgs gk = {p[4], p[5], p[6], p[7], nullptr, p[10], p[11], 2, DMODEL};
            gemm_nt3<<<gg2, gb, 0, stream>>>(gq, gk, gk);
        }
        {   // Wv, value, Wo (into p6/p7, freed by QK gemm)
            CArgs cc;
            cc.s[0] = Wv;    cc.h[0] = BH(p[0]); cc.l[0] = BH(p[1]); cc.sc[0] = 1.0f;
            cc.s[1] = value; cc.h[1] = BH(p[2]); cc.l[1] = BH(p[3]); cc.sc[1] = 1.0f;
            cc.s[2] = Wo;    cc.h[2] = BH(p[6]); cc.l[2] = BH(p[7]); cc.sc[2] = 1.0f;
            convN<<<dim3(cgx, 3), 256, 0, stream>>>(cc);
        }
        {   // vhT = Wv @ value^T
            GArgs gv = {p[0], p[1], p[2], p[3], nullptr, p[4], nullptr, 1, DMODEL};
            gemm_nt3<<<gg, gb, 0, stream>>>(gv, gv, gv);
        }
        attn_mfma<<<dim3(S_LEN / 128, NHEAD), 512, 0, stream>>>(
            p[8], p[9], p[10], p[11], p[4], scalars, p[8], p[9]);
        {   // out = attn_out @ Wo^T, split-K=2 (planes 0-3 free after V gemm)
            float* part0 = (float*)p[0];
            float* part1 = (float*)p[2];
            GArgs go0 = {p[8], p[9], p[6], p[7], part0, nullptr, nullptr, 0, 1024};
            GArgs go1 = {p[8] + 1024, p[9] + 1024, p[6] + 1024, p[7] + 1024,
                         part1, nullptr, nullptr, 0, 1024};
            gemm_nt3<<<gg2, gb, 0, stream>>>(go0, go1, go1);
            addf4<<<dim3(2048 * 2048 / 4 / 256), 256, 0, stream>>>(out, part0, part1);
        }
    }
#undef BH
}